// Round 1
// baseline (391.533 us; speedup 1.0000x reference)
//
#include <hip/hip_runtime.h>
#include <hip/hip_bf16.h>

#define H_ 256
#define N_ 64
#define L_ 2048
#define B_ 4
#define PI_ 3.14159265358979323846

// ---------------------------------------------------------------------------
// Kernel A: at_roots[h][l] = c[l] * (k00 - k01*k10/(1+k11))  (complex, f64 math)
// one thread per (h,l); block covers 256 consecutive l within one h.
// ---------------------------------------------------------------------------
__global__ __launch_bounds__(256) void cauchy_at_roots(
    const float* __restrict__ p_ri, const float* __restrict__ q_ri,
    const float* __restrict__ lam_ri, const float* __restrict__ B_ri,
    const float* __restrict__ Ct_ri, const float* __restrict__ log_step,
    float2* __restrict__ at) {
  __shared__ double wsh[N_][8];   // w00r,w00i, w01r,w01i, w10r,w10i, w11r,w11i
  __shared__ double lamsh[N_][2];
  int idx = blockIdx.x * 256 + threadIdx.x;
  int h = idx >> 11;              // 2048 l per h, 8 blocks per h
  int l = idx & (L_ - 1);

  if (threadIdx.x < N_) {
    int n = threadIdx.x;
    double br  = B_ri[(h*N_+n)*2+0],  bi  = B_ri[(h*N_+n)*2+1];
    double ctr = Ct_ri[(h*N_+n)*2+0], cti = Ct_ri[(h*N_+n)*2+1];
    double pr  = p_ri[2*n+0],  pim = p_ri[2*n+1];
    double qr  = q_ri[2*n+0],  qim = q_ri[2*n+1];
    double a0r = ctr, a0i = -cti;    // conj(Ct)
    double a1r = qr,  a1i = -qim;    // conj(q)
    wsh[n][0] = a0r*br - a0i*bi;   wsh[n][1] = a0r*bi + a0i*br;    // w00 = conj(Ct)*B
    wsh[n][2] = a0r*pr - a0i*pim;  wsh[n][3] = a0r*pim + a0i*pr;   // w01 = conj(Ct)*p
    wsh[n][4] = a1r*br - a1i*bi;   wsh[n][5] = a1r*bi + a1i*br;    // w10 = conj(q)*B
    wsh[n][6] = a1r*pr - a1i*pim;  wsh[n][7] = a1r*pim + a1i*pr;   // w11 = conj(q)*p
    lamsh[n][0] = lam_ri[2*n+0];   lamsh[n][1] = lam_ri[2*n+1];
  }
  __syncthreads();

  double step = (double)expf(log_step[h]);
  double tos  = 2.0 / step;
  double theta = (PI_ / 1024.0) * (double)l;         // 2*pi*l/2048
  double wr = cos(theta), wi = sin(theta);
  // t = (1-w)/(1+w), c = 2/(1+w)   (f64: |1+w| ~ 1e-16 at l=1024 is safe)
  double nr = 1.0 - wr, ni = -wi;
  double dr = 1.0 + wr, di = wi;
  double invden = 1.0 / (dr*dr + di*di);
  double tr = (nr*dr + ni*di) * invden;
  double ti = (ni*dr - nr*di) * invden;
  double gr = tos * tr, gi = tos * ti;
  double cr = 2.0*dr*invden, ci = -2.0*di*invden;

  double k00r=0,k00i=0,k01r=0,k01i=0,k10r=0,k10i=0,k11r=0,k11i=0;
  #pragma unroll 8
  for (int n = 0; n < N_; ++n) {
    double ddr = gr - lamsh[n][0];
    double ddi = gi - lamsh[n][1];
    double id  = 1.0 / (ddr*ddr + ddi*ddi);
    double rr  = ddr * id, ri = -ddi * id;           // r = 1/(g - lam)
    double w0r = wsh[n][0], w0i = wsh[n][1];
    double w1r = wsh[n][2], w1i = wsh[n][3];
    double w2r = wsh[n][4], w2i = wsh[n][5];
    double w3r = wsh[n][6], w3i = wsh[n][7];
    k00r += w0r*rr - w0i*ri;  k00i += w0r*ri + w0i*rr;
    k01r += w1r*rr - w1i*ri;  k01i += w1r*ri + w1i*rr;
    k10r += w2r*rr - w2i*ri;  k10i += w2r*ri + w2i*rr;
    k11r += w3r*rr - w3i*ri;  k11i += w3r*ri + w3i*rr;
  }
  // at = c * (k00 - k01*k10/(1+k11))
  double e1r = 1.0 + k11r, e1i = k11i;
  double ide = 1.0 / (e1r*e1r + e1i*e1i);
  double qr_ = k01r*k10r - k01i*k10i;
  double qi_ = k01r*k10i + k01i*k10r;
  double sr  = (qr_*e1r + qi_*e1i) * ide;
  double si  = (qi_*e1r - qr_*e1i) * ide;
  double fr  = k00r - sr, fi = k00i - si;
  double ar  = cr*fr - ci*fi;
  double ai  = cr*fi + ci*fr;
  at[h*L_ + l] = make_float2((float)ar, (float)ai);
}

// ---------------------------------------------------------------------------
// Kernel B: K[h,t] = Re( FFT_2048(at_roots[h,:])[t] ) / 2048
// (ifft + flip + roll(1) + real == forward-DFT real part / L)
// One block (256 thr) per h; radix-2 DIT FFT in LDS.
// ---------------------------------------------------------------------------
__global__ __launch_bounds__(256) void fft_k(
    const float2* __restrict__ at, float* __restrict__ K) {
  __shared__ float2 data[L_];       // 16 KB
  __shared__ float2 wtab[L_ / 2];   // 8 KB : wtab[k] = exp(-2*pi*i*k/2048)
  int h = blockIdx.x;
  int tid = threadIdx.x;

  for (int i = tid; i < L_/2; i += 256) {
    double ang = -(PI_ / 1024.0) * (double)i;
    wtab[i] = make_float2((float)cos(ang), (float)sin(ang));
  }
  for (int i = tid; i < L_; i += 256) {
    unsigned r = __brev((unsigned)i) >> 21;  // 11-bit reversal
    data[r] = at[h*L_ + i];
  }
  __syncthreads();

  for (int m = 2; m <= L_; m <<= 1) {
    int half = m >> 1;
    int tstep = L_ / m;
    for (int bfly = tid; bfly < L_/2; bfly += 256) {
      int pos = bfly & (half - 1);
      int i0  = ((bfly ^ pos) << 1) + pos;   // (bfly/half)*m + pos
      float2 w = wtab[pos * tstep];
      float2 a = data[i0];
      float2 b = data[i0 + half];
      float trr = w.x*b.x - w.y*b.y;
      float tii = w.x*b.y + w.y*b.x;
      data[i0]        = make_float2(a.x + trr, a.y + tii);
      data[i0 + half] = make_float2(a.x - trr, a.y - tii);
    }
    __syncthreads();
  }
  for (int i = tid; i < L_; i += 256)
    K[h*L_ + i] = data[i].x * (1.0f / (float)L_);
}

// ---------------------------------------------------------------------------
// Kernel C: y[b,t,h] = sum_{s=0..t} K[h,s]*u[b,t-s,h] + D[h]*u[b,t,h]
// Block: 16 h x 128 t outputs; s staged in chunks of 128 through LDS.
// Kw padded to stride 257 (breaks 16-way bank conflict -> <=2-way, free).
// ---------------------------------------------------------------------------
#define HT 16
#define TT 128
#define SC 128
__global__ __launch_bounds__(256) void causal_conv(
    const float* __restrict__ u, const float* __restrict__ Kt,
    const float* __restrict__ D, float* __restrict__ y) {
  __shared__ float us[SC][HT];        // 8 KB
  __shared__ float Kw[HT][257];       // 16.06 KB (padded stride)
  int b  = blockIdx.z;
  int h0 = blockIdx.y * HT;
  int t0 = blockIdx.x * TT;
  int tid = threadIdx.x;
  int tx = tid & 15;        // h within tile
  int ty = tid >> 4;        // t-subgroup (0..15), 8 t's each

  float acc[8] = {0.f,0.f,0.f,0.f,0.f,0.f,0.f,0.f};

  for (int s0 = 0; s0 <= t0; s0 += SC) {
    int d = t0 - s0;
    for (int i = tid; i < SC*HT; i += 256) {
      int s = i >> 4, hh = i & 15;
      us[s][hh] = u[(b*L_ + s0 + s)*H_ + h0 + hh];
    }
    for (int i = tid; i < HT*256; i += 256) {
      int hh = i >> 8, col = i & 255;
      int kidx = d - 127 + col;                 // = t - s at read time
      Kw[hh][col] = (kidx >= 0 && kidx < L_) ? Kt[(h0+hh)*L_ + kidx] : 0.0f;
    }
    __syncthreads();

    for (int s = 0; s < SC; ++s) {
      float uk = us[s][tx];
      int base = 127 + (ty << 3) - s;           // col for j=0; in [0,254]
      #pragma unroll
      for (int j = 0; j < 8; ++j)
        acc[j] = fmaf(Kw[tx][base + j], uk, acc[j]);
    }
    __syncthreads();
  }

  float Dh = D[h0 + tx];
  #pragma unroll
  for (int j = 0; j < 8; ++j) {
    int t  = t0 + (ty << 3) + j;
    int oi = (b*L_ + t)*H_ + h0 + tx;
    y[oi] = acc[j] + Dh * u[oi];
  }
}

// ---------------------------------------------------------------------------
extern "C" void kernel_launch(void* const* d_in, const int* in_sizes, int n_in,
                              void* d_out, int out_size, void* d_ws, size_t ws_size,
                              hipStream_t stream) {
  const float* u        = (const float*)d_in[0];
  const float* p_ri     = (const float*)d_in[1];
  const float* q_ri     = (const float*)d_in[2];
  const float* lam_ri   = (const float*)d_in[3];
  const float* B_ri     = (const float*)d_in[4];
  const float* Ct_ri    = (const float*)d_in[5];
  const float* D        = (const float*)d_in[6];
  const float* log_step = (const float*)d_in[7];
  float* y = (float*)d_out;

  char* ws = (char*)d_ws;
  float2* at = (float2*)ws;                              // H*L complex = 4 MB
  float*  Kt = (float*)(ws + (size_t)H_*L_*sizeof(float2)); // H*L f32   = 2 MB

  (void)in_sizes; (void)n_in; (void)out_size; (void)ws_size;

  cauchy_at_roots<<<dim3(H_*L_/256), dim3(256), 0, stream>>>(
      p_ri, q_ri, lam_ri, B_ri, Ct_ri, log_step, at);
  fft_k<<<dim3(H_), dim3(256), 0, stream>>>(at, Kt);
  causal_conv<<<dim3(L_/TT, H_/HT, B_), dim3(256), 0, stream>>>(u, Kt, D, y);
}

// Round 4
// 290.415 us; speedup vs baseline: 1.3482x; 1.3482x over previous
//
#include <hip/hip_runtime.h>
#include <hip/hip_bf16.h>

#define H_ 256
#define N_ 64
#define L_ 2048
#define B_ 4
#define PI_ 3.14159265358979323846

// ---------------------------------------------------------------------------
// Kernel A: at_roots[h][l] = c[l] * (k00 - k01*k10/(1+k11))   (all f32)
// Bilinear-transform identities (exact, no cancellation):
//   g = (2/step) * (1-w)/(1+w) = -i * (2/step) * tan(pi*l/L)
//   c = 2/(1+w)                =  1 - i * tan(pi*l/L)
// ---------------------------------------------------------------------------
__global__ __launch_bounds__(256) void cauchy_at_roots(
    const float* __restrict__ p_ri, const float* __restrict__ q_ri,
    const float* __restrict__ lam_ri, const float* __restrict__ B_ri,
    const float* __restrict__ Ct_ri, const float* __restrict__ log_step,
    float2* __restrict__ at) {
  __shared__ float wsh[N_][8];    // w00r,i  w01r,i  w10r,i  w11r,i
  __shared__ float lamsh[N_][2];
  int idx = blockIdx.x * 256 + threadIdx.x;
  int h = idx >> 11;              // 8 blocks per h
  int l = idx & (L_ - 1);

  if (threadIdx.x < N_) {
    int n = threadIdx.x;
    float br  = B_ri[(h*N_+n)*2+0],  bi  = B_ri[(h*N_+n)*2+1];
    float ctr = Ct_ri[(h*N_+n)*2+0], cti = Ct_ri[(h*N_+n)*2+1];
    float pr  = p_ri[2*n+0],  pim = p_ri[2*n+1];
    float qr  = q_ri[2*n+0],  qim = q_ri[2*n+1];
    float a0r = ctr, a0i = -cti;    // conj(Ct)
    float a1r = qr,  a1i = -qim;    // conj(q)
    wsh[n][0] = a0r*br - a0i*bi;   wsh[n][1] = a0r*bi + a0i*br;
    wsh[n][2] = a0r*pr - a0i*pim;  wsh[n][3] = a0r*pim + a0i*pr;
    wsh[n][4] = a1r*br - a1i*bi;   wsh[n][5] = a1r*bi + a1i*br;
    wsh[n][6] = a1r*pr - a1i*pim;  wsh[n][7] = a1r*pim + a1i*pr;
    lamsh[n][0] = lam_ri[2*n+0];   lamsh[n][1] = lam_ri[2*n+1];
  }
  __syncthreads();

  float step = expf(log_step[h]);
  float tn   = tanf((float)(PI_ / (double)L_) * (float)l);
  float G    = (2.0f / step) * tn;     // g = 0 - i*G
  float cr   = 1.0f, ci = -tn;         // c = 1 - i*tn

  float k00r=0.f,k00i=0.f,k01r=0.f,k01i=0.f,k10r=0.f,k10i=0.f,k11r=0.f,k11i=0.f;
  #pragma unroll 8
  for (int n = 0; n < N_; ++n) {
    float ddr = -lamsh[n][0];
    float ddi = -G - lamsh[n][1];
    float id  = 1.0f / (ddr*ddr + ddi*ddi);   // |ddi| <= ~2e10 -> sq <= 4e20, safe
    float rr  = ddr * id, ri = -ddi * id;     // r = 1/(g - lam)
    float w0r = wsh[n][0], w0i = wsh[n][1];
    float w1r = wsh[n][2], w1i = wsh[n][3];
    float w2r = wsh[n][4], w2i = wsh[n][5];
    float w3r = wsh[n][6], w3i = wsh[n][7];
    k00r = fmaf(w0r,rr,fmaf(-w0i,ri,k00r));  k00i = fmaf(w0r,ri,fmaf(w0i,rr,k00i));
    k01r = fmaf(w1r,rr,fmaf(-w1i,ri,k01r));  k01i = fmaf(w1r,ri,fmaf(w1i,rr,k01i));
    k10r = fmaf(w2r,rr,fmaf(-w2i,ri,k10r));  k10i = fmaf(w2r,ri,fmaf(w2i,rr,k10i));
    k11r = fmaf(w3r,rr,fmaf(-w3i,ri,k11r));  k11i = fmaf(w3r,ri,fmaf(w3i,rr,k11i));
  }
  float e1r = 1.0f + k11r, e1i = k11i;
  float ide = 1.0f / (e1r*e1r + e1i*e1i);
  float qr_ = k01r*k10r - k01i*k10i;
  float qi_ = k01r*k10i + k01i*k10r;
  float sr  = (qr_*e1r + qi_*e1i) * ide;
  float si  = (qi_*e1r - qr_*e1i) * ide;
  float fr  = k00r - sr, fi = k00i - si;
  at[h*L_ + l] = make_float2(cr*fr - ci*fi, cr*fi + ci*fr);
}

// ---------------------------------------------------------------------------
// Kernel B: K[h,t] = Re( FFT_2048(at_roots[h,:])[t] ) / 2048
// ---------------------------------------------------------------------------
__global__ __launch_bounds__(256) void fft_k(
    const float2* __restrict__ at, float* __restrict__ K) {
  __shared__ float2 data[L_];       // 16 KB
  __shared__ float2 wtab[L_ / 2];   // 8 KB
  int h = blockIdx.x;
  int tid = threadIdx.x;

  for (int i = tid; i < L_/2; i += 256) {
    float s, c;
    sincosf(-(float)(PI_ / 1024.0) * (float)i, &s, &c);
    wtab[i] = make_float2(c, s);
  }
  for (int i = tid; i < L_; i += 256) {
    unsigned r = __brev((unsigned)i) >> 21;
    data[r] = at[h*L_ + i];
  }
  __syncthreads();

  for (int m = 2; m <= L_; m <<= 1) {
    int half = m >> 1;
    int tstep = L_ / m;
    for (int bfly = tid; bfly < L_/2; bfly += 256) {
      int pos = bfly & (half - 1);
      int i0  = ((bfly ^ pos) << 1) + pos;
      float2 w = wtab[pos * tstep];
      float2 a = data[i0];
      float2 b = data[i0 + half];
      float trr = w.x*b.x - w.y*b.y;
      float tii = w.x*b.y + w.y*b.x;
      data[i0]        = make_float2(a.x + trr, a.y + tii);
      data[i0 + half] = make_float2(a.x - trr, a.y - tii);
    }
    __syncthreads();
  }
  for (int i = tid; i < L_; i += 256)
    K[h*L_ + i] = data[i].x * (1.0f / (float)L_);
}

// ---------------------------------------------------------------------------
// Kernel C: y[b,t,h] = sum_{s<=t} K[h,t-s]*u[b,s,h] + D[h]*u[b,t,h]
// Register-tiled: per thread 8 t-outputs; per 8-s sub-chunk read u[8] (2xb128)
// + K-window[16] (4xb128) -> 64 FMAs. Strides 132/260 keep b128 phases even.
// Reversed blockIdx.x: biggest-t0 (most chunks) blocks start first.
// ---------------------------------------------------------------------------
#define HT 16
#define TT 128
#define SC 128
#define USTR 132
#define KSTR 260
__global__ __launch_bounds__(256) void causal_conv(
    const float* __restrict__ u, const float* __restrict__ Kt,
    const float* __restrict__ D, float* __restrict__ y) {
  __shared__ float us[HT][USTR];    // 8.4 KB, us[h][s]
  __shared__ float Kw[HT][KSTR];    // 16.6 KB, col <-> d = t-s, d = d0-128+col
  int b  = blockIdx.z;
  int h0 = blockIdx.y * HT;
  int t0 = ((int)gridDim.x - 1 - (int)blockIdx.x) * TT;
  int tid = (int)threadIdx.x;
  int tx = tid & 15;            // h within tile
  int ty = tid >> 4;            // t-group: outputs T0..T0+7
  int T0 = t0 + ty * 8;

  float acc[8] = {0.f,0.f,0.f,0.f,0.f,0.f,0.f,0.f};

  for (int s0 = 0; s0 <= t0; s0 += SC) {
    int d0 = t0 - s0;
    // --- stage u (transpose [s][h] -> us[h][s]), float4 global loads ---
    {
      int f = tid;
      #pragma unroll
      for (int it = 0; it < 2; ++it, f += 256) {
        int s = f >> 2, hq = (f & 3) * 4;
        const float4 v = *(const float4*)&u[((size_t)b*L_ + s0 + s)*H_ + h0 + hq];
        us[hq+0][s] = v.x; us[hq+1][s] = v.y; us[hq+2][s] = v.z; us[hq+3][s] = v.w;
      }
    }
    // --- stage K window cols 0..255 (kidx = d0-128+col; <0 -> 0) ---
    {
      int f = tid;
      #pragma unroll
      for (int it = 0; it < 4; ++it, f += 256) {
        int hh = f >> 6, c4 = (f & 63) * 4;
        int kidx = d0 - 128 + c4;                  // d0 % 128 == 0 -> aligned
        float4 v = make_float4(0.f, 0.f, 0.f, 0.f);
        if (kidx >= 0) v = *(const float4*)&Kt[(size_t)(h0+hh)*L_ + kidx];
        *(float4*)&Kw[hh][c4] = v;
      }
    }
    __syncthreads();

    const float* usrow = &us[tx][0];
    const float* kwrow = &Kw[tx][0];
    #pragma unroll 2
    for (int ss = 0; ss < 16; ++ss) {
      float4 ua = *(const float4*)&usrow[8*ss];
      float4 ub = *(const float4*)&usrow[8*ss + 4];
      int Wc = 120 + 8*ty - 8*ss;                  // in [0,240], mod 8 == 0
      float kv[16];
      *(float4*)&kv[0]  = *(const float4*)&kwrow[Wc];
      *(float4*)&kv[4]  = *(const float4*)&kwrow[Wc + 4];
      *(float4*)&kv[8]  = *(const float4*)&kwrow[Wc + 8];
      *(float4*)&kv[12] = *(const float4*)&kwrow[Wc + 12];
      float uu[8] = {ua.x, ua.y, ua.z, ua.w, ub.x, ub.y, ub.z, ub.w};
      #pragma unroll
      for (int j = 0; j < 8; ++j) {
        #pragma unroll
        for (int k = 0; k < 8; ++k)
          acc[j] = fmaf(kv[8 + j - k], uu[k], acc[j]);   // d = T0+j-(s8+k)
      }
    }
    __syncthreads();
  }

  float Dh = D[h0 + tx];
  #pragma unroll
  for (int j = 0; j < 8; ++j) {
    size_t oi = ((size_t)b*L_ + (T0 + j))*H_ + h0 + tx;
    y[oi] = acc[j] + Dh * u[oi];
  }
}

// ---------------------------------------------------------------------------
extern "C" void kernel_launch(void* const* d_in, const int* in_sizes, int n_in,
                              void* d_out, int out_size, void* d_ws, size_t ws_size,
                              hipStream_t stream) {
  const float* u        = (const float*)d_in[0];
  const float* p_ri     = (const float*)d_in[1];
  const float* q_ri     = (const float*)d_in[2];
  const float* lam_ri   = (const float*)d_in[3];
  const float* B_ri     = (const float*)d_in[4];
  const float* Ct_ri    = (const float*)d_in[5];
  const float* D        = (const float*)d_in[6];
  const float* log_step = (const float*)d_in[7];
  float* y = (float*)d_out;

  char* ws = (char*)d_ws;
  float2* at = (float2*)ws;                                 // 4 MB
  float*  Kt = (float*)(ws + (size_t)H_*L_*sizeof(float2)); // 2 MB

  (void)in_sizes; (void)n_in; (void)out_size; (void)ws_size;

  cauchy_at_roots<<<dim3(H_*L_/256), dim3(256), 0, stream>>>(
      p_ri, q_ri, lam_ri, B_ri, Ct_ri, log_step, at);
  fft_k<<<dim3(H_), dim3(256), 0, stream>>>(at, Kt);
  causal_conv<<<dim3(L_/TT, H_/HT, B_), dim3(256), 0, stream>>>(u, Kt, D, y);
}

// Round 7
// 215.417 us; speedup vs baseline: 1.8176x; 1.3482x over previous
//
#include <hip/hip_runtime.h>
#include <hip/hip_bf16.h>

#define H_ 256
#define N_ 64
#define L_ 2048
#define B_ 4
#define PI_ 3.14159265358979323846

// ---------------------------------------------------------------------------
// Kernel A: at_roots[h][l] = c[l] * (k00 - k01*k10/(1+k11))   (all f32)
//   g = -i * (2/step) * tan(pi*l/L),  c = 1 - i*tan(pi*l/L)
// ---------------------------------------------------------------------------
__global__ __launch_bounds__(256) void cauchy_at_roots(
    const float* __restrict__ p_ri, const float* __restrict__ q_ri,
    const float* __restrict__ lam_ri, const float* __restrict__ B_ri,
    const float* __restrict__ Ct_ri, const float* __restrict__ log_step,
    float2* __restrict__ at) {
  __shared__ float wsh[N_][8];
  __shared__ float lamsh[N_][2];
  int idx = blockIdx.x * 256 + threadIdx.x;
  int h = idx >> 11;
  int l = idx & (L_ - 1);

  if (threadIdx.x < N_) {
    int n = threadIdx.x;
    float br  = B_ri[(h*N_+n)*2+0],  bi  = B_ri[(h*N_+n)*2+1];
    float ctr = Ct_ri[(h*N_+n)*2+0], cti = Ct_ri[(h*N_+n)*2+1];
    float pr  = p_ri[2*n+0],  pim = p_ri[2*n+1];
    float qr  = q_ri[2*n+0],  qim = q_ri[2*n+1];
    float a0r = ctr, a0i = -cti;
    float a1r = qr,  a1i = -qim;
    wsh[n][0] = a0r*br - a0i*bi;   wsh[n][1] = a0r*bi + a0i*br;
    wsh[n][2] = a0r*pr - a0i*pim;  wsh[n][3] = a0r*pim + a0i*pr;
    wsh[n][4] = a1r*br - a1i*bi;   wsh[n][5] = a1r*bi + a1i*br;
    wsh[n][6] = a1r*pr - a1i*pim;  wsh[n][7] = a1r*pim + a1i*pr;
    lamsh[n][0] = lam_ri[2*n+0];   lamsh[n][1] = lam_ri[2*n+1];
  }
  __syncthreads();

  float step = expf(log_step[h]);
  float tn   = tanf((float)(PI_ / (double)L_) * (float)l);
  float G    = (2.0f / step) * tn;
  float cr   = 1.0f, ci = -tn;

  float k00r=0.f,k00i=0.f,k01r=0.f,k01i=0.f,k10r=0.f,k10i=0.f,k11r=0.f,k11i=0.f;
  #pragma unroll 8
  for (int n = 0; n < N_; ++n) {
    float ddr = -lamsh[n][0];
    float ddi = -G - lamsh[n][1];
    float id  = 1.0f / (ddr*ddr + ddi*ddi);
    float rr  = ddr * id, ri = -ddi * id;
    float w0r = wsh[n][0], w0i = wsh[n][1];
    float w1r = wsh[n][2], w1i = wsh[n][3];
    float w2r = wsh[n][4], w2i = wsh[n][5];
    float w3r = wsh[n][6], w3i = wsh[n][7];
    k00r = fmaf(w0r,rr,fmaf(-w0i,ri,k00r));  k00i = fmaf(w0r,ri,fmaf(w0i,rr,k00i));
    k01r = fmaf(w1r,rr,fmaf(-w1i,ri,k01r));  k01i = fmaf(w1r,ri,fmaf(w1i,rr,k01i));
    k10r = fmaf(w2r,rr,fmaf(-w2i,ri,k10r));  k10i = fmaf(w2r,ri,fmaf(w2i,rr,k10i));
    k11r = fmaf(w3r,rr,fmaf(-w3i,ri,k11r));  k11i = fmaf(w3r,ri,fmaf(w3i,rr,k11i));
  }
  float e1r = 1.0f + k11r, e1i = k11i;
  float ide = 1.0f / (e1r*e1r + e1i*e1i);
  float qr_ = k01r*k10r - k01i*k10i;
  float qi_ = k01r*k10i + k01i*k10r;
  float sr  = (qr_*e1r + qi_*e1i) * ide;
  float si  = (qi_*e1r - qr_*e1i) * ide;
  float fr  = k00r - sr, fi = k00i - si;
  at[h*L_ + l] = make_float2(cr*fr - ci*fi, cr*fi + ci*fr);
}

// ---------------------------------------------------------------------------
// Kernel B: K[h,t] = Re( FFT_2048(at_roots[h,:])[t] ) / 2048
// ---------------------------------------------------------------------------
__global__ __launch_bounds__(256) void fft_k(
    const float2* __restrict__ at, float* __restrict__ K) {
  __shared__ float2 data[L_];
  __shared__ float2 wtab[L_ / 2];
  int h = blockIdx.x;
  int tid = threadIdx.x;

  for (int i = tid; i < L_/2; i += 256) {
    float s, c;
    sincosf(-(float)(PI_ / 1024.0) * (float)i, &s, &c);
    wtab[i] = make_float2(c, s);
  }
  for (int i = tid; i < L_; i += 256) {
    unsigned r = __brev((unsigned)i) >> 21;
    data[r] = at[h*L_ + i];
  }
  __syncthreads();

  for (int m = 2; m <= L_; m <<= 1) {
    int half = m >> 1;
    int tstep = L_ / m;
    for (int bfly = tid; bfly < L_/2; bfly += 256) {
      int pos = bfly & (half - 1);
      int i0  = ((bfly ^ pos) << 1) + pos;
      float2 w = wtab[pos * tstep];
      float2 a = data[i0];
      float2 b = data[i0 + half];
      float trr = w.x*b.x - w.y*b.y;
      float tii = w.x*b.y + w.y*b.x;
      data[i0]        = make_float2(a.x + trr, a.y + tii);
      data[i0 + half] = make_float2(a.x - trr, a.y - tii);
    }
    __syncthreads();
  }
  for (int i = tid; i < L_; i += 256)
    K[h*L_ + i] = data[i].x * (1.0f / (float)L_);
}

// ---------------------------------------------------------------------------
// Kernel C: y[b,t,h] = sum_{s<=t} K[h,t-s]*u[b,s,h] + D[h]*u[b,t,h]
// TT=256 t-tile, J=16 outputs/thread, SC=128 s-chunks.
// 2-phase pipeline: chunk c+1 global loads issue before chunk c compute;
// ds_write after barrier (T14 async-stage). Single LDS buffer, 33 KB.
// Reversed tile order -> hardware greedy == LPT (16 chunks/CU uniform).
// ---------------------------------------------------------------------------
#define HT 16
#define TT 256
#define SC 128
#define JT 16
#define USTR 132       // 33 float4 per row (odd) -> conflict-free b128
#define KSTR 388       // 97 float4 per row (odd)
__global__ __launch_bounds__(256) void causal_conv(
    const float* __restrict__ u, const float* __restrict__ Kt,
    const float* __restrict__ D, float* __restrict__ y) {
  __shared__ float us[HT][USTR];   // 8448 B   us[h][s]
  __shared__ float Kw[HT][KSTR];   // 24832 B  col c <-> kidx = d0-128+c, c in [0,384)
  int b  = blockIdx.z;
  int h0 = blockIdx.y * HT;
  int tile = (int)gridDim.x - 1 - (int)blockIdx.x;
  int t0 = tile * TT;
  int tid = (int)threadIdx.x;
  int tx = tid & 15;               // h within tile
  int ty = tid >> 4;               // 0..15, outputs T0..T0+15
  int T0 = t0 + ty * JT;
  int nchunks = t0 / SC + 1;       // = 2*tile + 1

  float acc[JT];
  #pragma unroll
  for (int j = 0; j < JT; ++j) acc[j] = 0.f;

  // staging registers
  float4 ustg0, ustg1;
  float4 kstg[6];
  // u-stage mapping: idx = tid + 256*it -> s = idx>>2, hq = (idx&3)*4
  int us_s0 = tid >> 2, us_h0 = (tid & 3) * 4;          // it=0
  int us_s1 = (tid + 256) >> 2, us_h1 = (tid & 3) * 4;  // it=1 (same hq)
  // K-stage mapping: row = ty, f4-col = tx + 16*it
  const float* Krow = &Kt[(size_t)(h0 + ty) * L_];

  // ---- prologue: issue chunk-0 loads ----
  {
    int s0 = 0, d0 = t0;
    ustg0 = *(const float4*)&u[((size_t)b*L_ + s0 + us_s0)*H_ + h0 + us_h0];
    ustg1 = *(const float4*)&u[((size_t)b*L_ + s0 + us_s1)*H_ + h0 + us_h1];
    #pragma unroll
    for (int it = 0; it < 6; ++it) {
      int kidx = d0 - 128 + 4*(tx + 16*it);
      kstg[it] = (kidx >= 0) ? *(const float4*)&Krow[kidx]
                             : make_float4(0.f,0.f,0.f,0.f);
    }
  }

  for (int c = 0; c < nchunks; ++c) {
    if (c) __syncthreads();        // previous compute done reading LDS
    // ---- write staged chunk c to LDS (compiler inserts vmcnt wait) ----
    us[us_h0+0][us_s0] = ustg0.x; us[us_h0+1][us_s0] = ustg0.y;
    us[us_h0+2][us_s0] = ustg0.z; us[us_h0+3][us_s0] = ustg0.w;
    us[us_h1+0][us_s1] = ustg1.x; us[us_h1+1][us_s1] = ustg1.y;
    us[us_h1+2][us_s1] = ustg1.z; us[us_h1+3][us_s1] = ustg1.w;
    #pragma unroll
    for (int it = 0; it < 6; ++it)
      *(float4*)&Kw[ty][4*(tx + 16*it)] = kstg[it];
    // ---- issue chunk c+1 loads early (hide under compute) ----
    if (c + 1 < nchunks) {
      int s0n = (c+1) * SC, d0n = t0 - s0n;
      ustg0 = *(const float4*)&u[((size_t)b*L_ + s0n + us_s0)*H_ + h0 + us_h0];
      ustg1 = *(const float4*)&u[((size_t)b*L_ + s0n + us_s1)*H_ + h0 + us_h1];
      #pragma unroll
      for (int it = 0; it < 6; ++it) {
        int kidx = d0n - 128 + 4*(tx + 16*it);
        kstg[it] = (kidx >= 0) ? *(const float4*)&Krow[kidx]
                               : make_float4(0.f,0.f,0.f,0.f);
      }
    }
    __syncthreads();
    // ---- compute chunk c ----
    const float* usrow = &us[tx][0];
    const float* kwrow = &Kw[tx][0];
    #pragma unroll 2
    for (int ss = 0; ss < 16; ++ss) {
      float4 ua = *(const float4*)&usrow[8*ss];
      float4 ub = *(const float4*)&usrow[8*ss + 4];
      int Wb = 120 + JT*ty - 8*ss;              // in [0,360], mod 4 == 0
      float kv[24];
      #pragma unroll
      for (int q = 0; q < 6; ++q)
        *(float4*)&kv[4*q] = *(const float4*)&kwrow[Wb + 4*q];
      float uu[8] = {ua.x, ua.y, ua.z, ua.w, ub.x, ub.y, ub.z, ub.w};
      #pragma unroll
      for (int j = 0; j < JT; ++j) {
        #pragma unroll
        for (int k = 0; k < 8; ++k)
          acc[j] = fmaf(kv[8 + j - k], uu[k], acc[j]);  // col = Wb+8+j-k
      }
    }
  }

  float Dh = D[h0 + tx];
  #pragma unroll
  for (int j = 0; j < JT; ++j) {
    size_t oi = ((size_t)b*L_ + (T0 + j))*H_ + h0 + tx;
    y[oi] = acc[j] + Dh * u[oi];
  }
}

// ---------------------------------------------------------------------------
extern "C" void kernel_launch(void* const* d_in, const int* in_sizes, int n_in,
                              void* d_out, int out_size, void* d_ws, size_t ws_size,
                              hipStream_t stream) {
  const float* u        = (const float*)d_in[0];
  const float* p_ri     = (const float*)d_in[1];
  const float* q_ri     = (const float*)d_in[2];
  const float* lam_ri   = (const float*)d_in[3];
  const float* B_ri     = (const float*)d_in[4];
  const float* Ct_ri    = (const float*)d_in[5];
  const float* D        = (const float*)d_in[6];
  const float* log_step = (const float*)d_in[7];
  float* y = (float*)d_out;

  char* ws = (char*)d_ws;
  float2* at = (float2*)ws;                                 // 4 MB
  float*  Kt = (float*)(ws + (size_t)H_*L_*sizeof(float2)); // 2 MB

  (void)in_sizes; (void)n_in; (void)out_size; (void)ws_size;

  cauchy_at_roots<<<dim3(H_*L_/256), dim3(256), 0, stream>>>(
      p_ri, q_ri, lam_ri, B_ri, Ct_ri, log_step, at);
  fft_k<<<dim3(H_), dim3(256), 0, stream>>>(at, Kt);
  causal_conv<<<dim3(L_/TT, H_/HT, B_), dim3(256), 0, stream>>>(u, Kt, D, y);
}

// Round 8
// 172.514 us; speedup vs baseline: 2.2696x; 1.2487x over previous
//
#include <hip/hip_runtime.h>
#include <hip/hip_bf16.h>

#define H_ 256
#define N_ 64
#define L_ 2048
#define B_ 4
#define PI_ 3.14159265358979323846

// ---------------------------------------------------------------------------
// Kernel A: at_roots[h][l] = c[l] * (k00 - k01*k10/(1+k11))   (all f32)
//   g = -i * (2/step) * tan(pi*l/L),  c = 1 - i*tan(pi*l/L)
// ---------------------------------------------------------------------------
__global__ __launch_bounds__(256) void cauchy_at_roots(
    const float* __restrict__ p_ri, const float* __restrict__ q_ri,
    const float* __restrict__ lam_ri, const float* __restrict__ B_ri,
    const float* __restrict__ Ct_ri, const float* __restrict__ log_step,
    float2* __restrict__ at) {
  __shared__ float wsh[N_][8];
  __shared__ float lamsh[N_][2];
  int idx = blockIdx.x * 256 + threadIdx.x;
  int h = idx >> 11;
  int l = idx & (L_ - 1);

  if (threadIdx.x < N_) {
    int n = threadIdx.x;
    float br  = B_ri[(h*N_+n)*2+0],  bi  = B_ri[(h*N_+n)*2+1];
    float ctr = Ct_ri[(h*N_+n)*2+0], cti = Ct_ri[(h*N_+n)*2+1];
    float pr  = p_ri[2*n+0],  pim = p_ri[2*n+1];
    float qr  = q_ri[2*n+0],  qim = q_ri[2*n+1];
    float a0r = ctr, a0i = -cti;
    float a1r = qr,  a1i = -qim;
    wsh[n][0] = a0r*br - a0i*bi;   wsh[n][1] = a0r*bi + a0i*br;
    wsh[n][2] = a0r*pr - a0i*pim;  wsh[n][3] = a0r*pim + a0i*pr;
    wsh[n][4] = a1r*br - a1i*bi;   wsh[n][5] = a1r*bi + a1i*br;
    wsh[n][6] = a1r*pr - a1i*pim;  wsh[n][7] = a1r*pim + a1i*pr;
    lamsh[n][0] = lam_ri[2*n+0];   lamsh[n][1] = lam_ri[2*n+1];
  }
  __syncthreads();

  float step = expf(log_step[h]);
  float tn   = tanf((float)(PI_ / (double)L_) * (float)l);
  float G    = (2.0f / step) * tn;
  float cr   = 1.0f, ci = -tn;

  float k00r=0.f,k00i=0.f,k01r=0.f,k01i=0.f,k10r=0.f,k10i=0.f,k11r=0.f,k11i=0.f;
  #pragma unroll 8
  for (int n = 0; n < N_; ++n) {
    float ddr = -lamsh[n][0];
    float ddi = -G - lamsh[n][1];
    float id  = 1.0f / (ddr*ddr + ddi*ddi);
    float rr  = ddr * id, ri = -ddi * id;
    float w0r = wsh[n][0], w0i = wsh[n][1];
    float w1r = wsh[n][2], w1i = wsh[n][3];
    float w2r = wsh[n][4], w2i = wsh[n][5];
    float w3r = wsh[n][6], w3i = wsh[n][7];
    k00r = fmaf(w0r,rr,fmaf(-w0i,ri,k00r));  k00i = fmaf(w0r,ri,fmaf(w0i,rr,k00i));
    k01r = fmaf(w1r,rr,fmaf(-w1i,ri,k01r));  k01i = fmaf(w1r,ri,fmaf(w1i,rr,k01i));
    k10r = fmaf(w2r,rr,fmaf(-w2i,ri,k10r));  k10i = fmaf(w2r,ri,fmaf(w2i,rr,k10i));
    k11r = fmaf(w3r,rr,fmaf(-w3i,ri,k11r));  k11i = fmaf(w3r,ri,fmaf(w3i,rr,k11i));
  }
  float e1r = 1.0f + k11r, e1i = k11i;
  float ide = 1.0f / (e1r*e1r + e1i*e1i);
  float qr_ = k01r*k10r - k01i*k10i;
  float qi_ = k01r*k10i + k01i*k10r;
  float sr  = (qr_*e1r + qi_*e1i) * ide;
  float si  = (qi_*e1r - qr_*e1i) * ide;
  float fr  = k00r - sr, fi = k00i - si;
  at[h*L_ + l] = make_float2(cr*fr - ci*fi, cr*fi + ci*fr);
}

// ---------------------------------------------------------------------------
// Kernel B: K[h,t] = Re( FFT_2048(at_roots[h,:])[t] ) / 2048   (512 threads)
// ---------------------------------------------------------------------------
__global__ __launch_bounds__(512) void fft_k(
    const float2* __restrict__ at, float* __restrict__ K) {
  __shared__ float2 data[L_];
  __shared__ float2 wtab[L_ / 2];
  int h = blockIdx.x;
  int tid = threadIdx.x;

  for (int i = tid; i < L_/2; i += 512) {
    float s, c;
    sincosf(-(float)(PI_ / 1024.0) * (float)i, &s, &c);
    wtab[i] = make_float2(c, s);
  }
  for (int i = tid; i < L_; i += 512) {
    unsigned r = __brev((unsigned)i) >> 21;
    data[r] = at[h*L_ + i];
  }
  __syncthreads();

  for (int m = 2; m <= L_; m <<= 1) {
    int half = m >> 1;
    int tstep = L_ / m;
    for (int bfly = tid; bfly < L_/2; bfly += 512) {
      int pos = bfly & (half - 1);
      int i0  = ((bfly ^ pos) << 1) + pos;
      float2 w = wtab[pos * tstep];
      float2 a = data[i0];
      float2 b = data[i0 + half];
      float trr = w.x*b.x - w.y*b.y;
      float tii = w.x*b.y + w.y*b.x;
      data[i0]        = make_float2(a.x + trr, a.y + tii);
      data[i0 + half] = make_float2(a.x - trr, a.y - tii);
    }
    __syncthreads();
  }
  for (int i = tid; i < L_; i += 512)
    K[h*L_ + i] = data[i].x * (1.0f / (float)L_);
}

// ---------------------------------------------------------------------------
// Kernel C: split-K causal conv. Tile pair (a, 7-a) has exactly 16 chunks
// (SC=128 within TT=256 tiles); split into 4 blocks x 4 chunks -> 1024
// perfectly uniform blocks = 4 blocks/CU, one residency generation.
// Partial sums atomicAdd'ed into y (pre-zeroed); D*u added by add_du.
// ---------------------------------------------------------------------------
#define HT 16
#define TT 256
#define SC 128
#define JT 16
#define USTR 132       // odd # of float4 per row -> conflict-balanced b128
#define KSTR 388

__device__ __forceinline__ void qmap(int p, int q, int& tile, int& c) {
  int nchA = 2*p + 1;                 // chunks in tile p
  if (q < nchA) { tile = p;     c = q; }
  else          { tile = 7 - p; c = q - nchA; }
}

__global__ __launch_bounds__(256, 4) void causal_conv_sk(
    const float* __restrict__ u, const float* __restrict__ Kt,
    float* __restrict__ y) {
  __shared__ float us[HT][USTR];   // 8448 B   us[h][s]
  __shared__ float Kw[HT][KSTR];   // 24832 B  col c <-> kidx = d0-128+c
  int b  = blockIdx.z;
  int h0 = blockIdx.y * HT;
  int gx = (int)blockIdx.x;        // 0..15
  int p  = gx >> 2;                // pair index 0..3
  int q0 = (gx & 3) * 4;           // first chunk slot of this block
  int tid = (int)threadIdx.x;
  int tx = tid & 15;               // h within tile
  int ty = tid >> 4;               // t-group, outputs T0..T0+15 of cur tile

  int us_s0 = tid >> 2, us_hq = (tid & 3) * 4;
  int us_s1 = us_s0 + 64;
  const float* Krow  = &Kt[(size_t)(h0 + ty) * L_];
  const float* ubase = &u[(size_t)b * L_ * H_];

  float acc[JT];
  #pragma unroll
  for (int j = 0; j < JT; ++j) acc[j] = 0.f;

  float4 ustg0, ustg1, kstg[6];

  int cur_tile, c;
  qmap(p, q0, cur_tile, c);
  {
    int s0 = c * SC, d0 = cur_tile * TT - s0;
    ustg0 = *(const float4*)&ubase[(size_t)(s0 + us_s0)*H_ + h0 + us_hq];
    ustg1 = *(const float4*)&ubase[(size_t)(s0 + us_s1)*H_ + h0 + us_hq];
    #pragma unroll
    for (int it = 0; it < 6; ++it) {
      int kidx = d0 - 128 + 4*(tx + 16*it);
      kstg[it] = (kidx >= 0) ? *(const float4*)&Krow[kidx]
                             : make_float4(0.f,0.f,0.f,0.f);
    }
  }

  for (int i = 0; i < 4; ++i) {
    if (i) __syncthreads();
    // ---- write staged chunk to LDS ----
    us[us_hq+0][us_s0] = ustg0.x; us[us_hq+1][us_s0] = ustg0.y;
    us[us_hq+2][us_s0] = ustg0.z; us[us_hq+3][us_s0] = ustg0.w;
    us[us_hq+0][us_s1] = ustg1.x; us[us_hq+1][us_s1] = ustg1.y;
    us[us_hq+2][us_s1] = ustg1.z; us[us_hq+3][us_s1] = ustg1.w;
    #pragma unroll
    for (int it = 0; it < 6; ++it)
      *(float4*)&Kw[ty][4*(tx + 16*it)] = kstg[it];
    // ---- issue next chunk's loads early ----
    int nxt_tile = -1;
    if (i < 3) {
      int c2; qmap(p, q0 + i + 1, nxt_tile, c2);
      int s0n = c2 * SC, d0n = nxt_tile * TT - s0n;
      ustg0 = *(const float4*)&ubase[(size_t)(s0n + us_s0)*H_ + h0 + us_hq];
      ustg1 = *(const float4*)&ubase[(size_t)(s0n + us_s1)*H_ + h0 + us_hq];
      #pragma unroll
      for (int it = 0; it < 6; ++it) {
        int kidx = d0n - 128 + 4*(tx + 16*it);
        kstg[it] = (kidx >= 0) ? *(const float4*)&Krow[kidx]
                               : make_float4(0.f,0.f,0.f,0.f);
      }
    }
    __syncthreads();
    // ---- compute chunk into acc ----
    const float* usrow = &us[tx][0];
    const float* kwrow = &Kw[tx][0];
    #pragma unroll 2
    for (int ss = 0; ss < 16; ++ss) {
      float4 ua = *(const float4*)&usrow[8*ss];
      float4 ub = *(const float4*)&usrow[8*ss + 4];
      int Wb = 120 + JT*ty - 8*ss;             // window base, d0-independent
      float kv[24];
      #pragma unroll
      for (int qq = 0; qq < 6; ++qq)
        *(float4*)&kv[4*qq] = *(const float4*)&kwrow[Wb + 4*qq];
      float uu[8] = {ua.x, ua.y, ua.z, ua.w, ub.x, ub.y, ub.z, ub.w};
      #pragma unroll
      for (int j = 0; j < JT; ++j) {
        #pragma unroll
        for (int kk = 0; kk < 8; ++kk)
          acc[j] = fmaf(kv[8 + j - kk], uu[kk], acc[j]);
      }
    }
    // ---- flush when tile changes (or at end) ----
    if (nxt_tile != cur_tile) {
      int T0 = cur_tile * TT + ty * JT;
      #pragma unroll
      for (int j = 0; j < JT; ++j)
        atomicAdd(&y[((size_t)b*L_ + T0 + j)*H_ + h0 + tx], acc[j]);
      #pragma unroll
      for (int j = 0; j < JT; ++j) acc[j] = 0.f;
      cur_tile = nxt_tile;
    }
  }
}

// ---------------------------------------------------------------------------
// Kernel D: y += D * u   (elementwise, float4)
// ---------------------------------------------------------------------------
__global__ __launch_bounds__(256) void add_du(
    const float* __restrict__ u, const float* __restrict__ D,
    float* __restrict__ y) {
  size_t i4 = ((size_t)blockIdx.x * 256 + threadIdx.x) * 4;
  float4 uv = *(const float4*)&u[i4];
  float4 yv = *(const float4*)&y[i4];
  int hh = (int)(i4 & (H_ - 1));
  float4 dv = *(const float4*)&D[hh];
  yv.x = fmaf(dv.x, uv.x, yv.x);
  yv.y = fmaf(dv.y, uv.y, yv.y);
  yv.z = fmaf(dv.z, uv.z, yv.z);
  yv.w = fmaf(dv.w, uv.w, yv.w);
  *(float4*)&y[i4] = yv;
}

// ---------------------------------------------------------------------------
extern "C" void kernel_launch(void* const* d_in, const int* in_sizes, int n_in,
                              void* d_out, int out_size, void* d_ws, size_t ws_size,
                              hipStream_t stream) {
  const float* u        = (const float*)d_in[0];
  const float* p_ri     = (const float*)d_in[1];
  const float* q_ri     = (const float*)d_in[2];
  const float* lam_ri   = (const float*)d_in[3];
  const float* B_ri     = (const float*)d_in[4];
  const float* Ct_ri    = (const float*)d_in[5];
  const float* D        = (const float*)d_in[6];
  const float* log_step = (const float*)d_in[7];
  float* y = (float*)d_out;

  char* ws = (char*)d_ws;
  float2* at = (float2*)ws;                                 // 4 MB
  float*  Kt = (float*)(ws + (size_t)H_*L_*sizeof(float2)); // 2 MB

  (void)in_sizes; (void)n_in; (void)out_size; (void)ws_size;

  hipMemsetAsync(y, 0, (size_t)B_*L_*H_*sizeof(float), stream);
  cauchy_at_roots<<<dim3(H_*L_/256), dim3(256), 0, stream>>>(
      p_ri, q_ri, lam_ri, B_ri, Ct_ri, log_step, at);
  fft_k<<<dim3(H_), dim3(512), 0, stream>>>(at, Kt);
  causal_conv_sk<<<dim3(16, H_/HT, B_), dim3(256), 0, stream>>>(u, Kt, y);
  add_du<<<dim3((B_*L_*H_/4)/256), dim3(256), 0, stream>>>(u, D, y);
}